// Round 1
// baseline (1039.724 us; speedup 1.0000x reference)
//
#include <hip/hip_runtime.h>
#include <stdint.h>

#define K_DIM 4096
#define N_DIM 11008
#define M_DIM 8192

constexpr int BM = 128, BN = 128, BK = 64;
constexpr int LDA = 72;            // padded bf16 elems per LDS row (+16B, bank-balanced)
constexpr int LDB = 72;
constexpr int NTILES = K_DIM / BK; // 64

static_assert(M_DIM % BM == 0 && N_DIM % BN == 0 && K_DIM % BK == 0, "tiling");

typedef __bf16 bf16x8_t __attribute__((ext_vector_type(8)));
typedef float  f32x4_t  __attribute__((ext_vector_type(4)));

__global__ __launch_bounds__(256, 2)
void qgemm_kernel(const float* __restrict__ x, const uint32_t* __restrict__ qw,
                  const uint32_t* __restrict__ qz, const float* __restrict__ sc,
                  const float* __restrict__ bias, float* __restrict__ out)
{
    __shared__ __bf16 As[BM * LDA];   // A tile, [m][k] k-contiguous
    __shared__ __bf16 Bs[BN * LDB];   // B^T tile, [n][k] k-contiguous

    const int tid = threadIdx.x;
    const int n0 = blockIdx.x * BN;   // N tile
    const int m0 = blockIdx.y * BM;   // M tile

    const int lane = tid & 63;
    const int wid  = tid >> 6;        // 0..3
    const int wr = wid >> 1;          // wave row 0..1 (64-row sub-tile)
    const int wc = wid & 1;           // wave col 0..1 (64-col sub-tile)
    const int lr = lane & 15;         // frag row (A) / col (B,C)
    const int lk = lane >> 4;         // k-chunk 0..3 (A/B), row-chunk (C)

    // A staging: element-pair p = i*256+tid -> row = i*32 + (tid>>3), colpair = tid&7
    const int arow = tid >> 3;
    const int acp  = tid & 7;
    // B staging: word wi = i*256+tid -> packed row r = 2*i + (tid>>7), col c = tid&127
    const int brow = tid >> 7;
    const int bcol = tid & 127;

    f32x4_t acc[4][4];
#pragma unroll
    for (int i = 0; i < 4; ++i)
#pragma unroll
        for (int j = 0; j < 4; ++j) {
            f32x4_t z = {0.0f, 0.0f, 0.0f, 0.0f};
            acc[i][j] = z;
        }

    // staging registers (prefetched one K-tile ahead)
    f32x4_t  areg[4][2];
    uint32_t breg[4];
    float    bscale_c = 0.0f, bsz_c = 0.0f;

    const float* xbase = x + (size_t)(m0 + arow) * K_DIM + acp * 8;

    auto load_tile = [&](int kt) {
        const float* ap = xbase + kt * BK;
#pragma unroll
        for (int i = 0; i < 4; ++i) {
            const float* src = ap + (size_t)(i * 32) * K_DIM;
            areg[i][0] = *(const f32x4_t*)(src);
            areg[i][1] = *(const f32x4_t*)(src + 4);
        }
        const int g = kt >> 1;        // group = (kt*64)/128
        const int n = n0 + bcol;
        const float s = sc[g * N_DIM + n];
        const uint32_t zw = qz[g * (N_DIM / 8) + (n >> 3)];
        bscale_c = s;
        bsz_c = s * (float)((zw >> (4 * (n & 7))) & 15u);
        const uint32_t* qp = qw + (size_t)(kt * 8 + brow) * N_DIM + n;
#pragma unroll
        for (int i = 0; i < 4; ++i)
            breg[i] = qp[(size_t)(2 * i) * N_DIM];
    };

    auto write_tile = [&]() {
        // A: convert fp32 -> bf16, 8 elems -> one ds_write_b128
#pragma unroll
        for (int i = 0; i < 4; ++i) {
            bf16x8_t v;
#pragma unroll
            for (int j = 0; j < 4; ++j) {
                v[j]     = (__bf16)areg[i][0][j];
                v[j + 4] = (__bf16)areg[i][1][j];
            }
            *(bf16x8_t*)&As[(arow + i * 32) * LDA + acp * 8] = v;
        }
        // B: unpack 8 nibbles (K-contiguous) -> dequant -> one ds_write_b128
#pragma unroll
        for (int i = 0; i < 4; ++i) {
            const uint32_t w = breg[i];
            bf16x8_t v;
#pragma unroll
            for (int j = 0; j < 8; ++j) {
                const float q = (float)((w >> (4 * j)) & 15u);
                v[j] = (__bf16)__builtin_fmaf(q, bscale_c, -bsz_c);
            }
            *(bf16x8_t*)&Bs[bcol * LDB + (brow + 2 * i) * 8] = v;
        }
    };

    load_tile(0);

    for (int kt = 0; kt < NTILES; ++kt) {
        __syncthreads();              // previous compute done reading LDS
        write_tile();
        __syncthreads();              // LDS tile ready
        if (kt + 1 < NTILES) load_tile(kt + 1);   // prefetch next (hides HBM under MFMA)

#pragma unroll
        for (int ks = 0; ks < 2; ++ks) {
            bf16x8_t af[4], bfr[4];
#pragma unroll
            for (int i = 0; i < 4; ++i)
                af[i] = *(const bf16x8_t*)&As[(wr * 64 + i * 16 + lr) * LDA + ks * 32 + lk * 8];
#pragma unroll
            for (int j = 0; j < 4; ++j)
                bfr[j] = *(const bf16x8_t*)&Bs[(wc * 64 + j * 16 + lr) * LDB + ks * 32 + lk * 8];
#pragma unroll
            for (int i = 0; i < 4; ++i)
#pragma unroll
                for (int j = 0; j < 4; ++j)
                    acc[i][j] = __builtin_amdgcn_mfma_f32_16x16x32_bf16(af[i], bfr[j], acc[i][j], 0, 0, 0);
        }
    }

    // Epilogue: C/D layout col = lane&15, row = (lane>>4)*4 + reg  [m89-verified]
    const int ccol0 = n0 + wc * 64 + lr;
    float bj[4];
#pragma unroll
    for (int j = 0; j < 4; ++j) bj[j] = bias[ccol0 + j * 16];

#pragma unroll
    for (int i = 0; i < 4; ++i) {
        const int rbase = m0 + wr * 64 + i * 16 + lk * 4;
#pragma unroll
        for (int j = 0; j < 4; ++j) {
            const int col = ccol0 + j * 16;
#pragma unroll
            for (int r = 0; r < 4; ++r)
                out[(size_t)(rbase + r) * N_DIM + col] = acc[i][j][r] + bj[j];
        }
    }
}

extern "C" void kernel_launch(void* const* d_in, const int* in_sizes, int n_in,
                              void* d_out, int out_size, void* d_ws, size_t ws_size,
                              hipStream_t stream) {
    const float*    xp = (const float*)d_in[0];
    const uint32_t* qw = (const uint32_t*)d_in[1];
    const uint32_t* qz = (const uint32_t*)d_in[2];
    const float*    sc = (const float*)d_in[3];
    const float*    bi = (const float*)d_in[4];
    float*          op = (float*)d_out;
    (void)in_sizes; (void)n_in; (void)d_ws; (void)ws_size; (void)out_size;

    dim3 grid(N_DIM / BN, M_DIM / BM);   // x = N tiles (86), y = M tiles (64)
    qgemm_kernel<<<grid, dim3(256), 0, stream>>>(xp, qw, qz, sc, bi, op);
}

// Round 2
// 992.415 us; speedup vs baseline: 1.0477x; 1.0477x over previous
//
#include <hip/hip_runtime.h>
#include <stdint.h>

#define K_DIM 4096
#define N_DIM 11008
#define M_DIM 8192

constexpr int BM = 128, BN = 128, BK = 64;
constexpr int LDA = 72;            // f16 elems/row: 144 B stride, 16B-aligned, bank-spread
constexpr int NT  = K_DIM / BK;    // 64
constexpr int NZW = N_DIM / 8;     // 1376
constexpr int NXT = N_DIM / BN;    // 86
constexpr int MXT = M_DIM / BM;    // 64
constexpr int NWG = NXT * MXT;     // 5504 = 8 * 688 (exactly divisible -> bijective swizzle)

typedef _Float16 f16x2 __attribute__((ext_vector_type(2)));
typedef _Float16 f16x8 __attribute__((ext_vector_type(8)));
typedef float    f32x4 __attribute__((ext_vector_type(4)));

union H8 { f16x8 v; f16x2 p[4]; };

// word w holds nibbles n0..n7 (k-offsets 0..7). Produces f16x8 in k-order
// (0,4,1,5,2,6,3,7) — A is staged with the identical permutation.
__device__ __forceinline__ f16x8 dq_word(uint32_t w, f16x2 ss, f16x2 zz) {
    H8 r;
    uint32_t t0 = ( w        & 0x000F000Fu) | 0x64006400u;  // (1024+n0, 1024+n4)
    uint32_t t1 = ((w >> 4)  & 0x000F000Fu) | 0x64006400u;
    uint32_t t2 = ((w >> 8)  & 0x000F000Fu) | 0x64006400u;
    uint32_t t3 = ((w >> 12) & 0x000F000Fu) | 0x64006400u;
    r.p[0] = (__builtin_bit_cast(f16x2, t0) - zz) * ss;     // exact: s*(q-z)
    r.p[1] = (__builtin_bit_cast(f16x2, t1) - zz) * ss;
    r.p[2] = (__builtin_bit_cast(f16x2, t2) - zz) * ss;
    r.p[3] = (__builtin_bit_cast(f16x2, t3) - zz) * ss;
    return r.v;
}

__global__ __launch_bounds__(256, 3)
void qgemm_kernel(const float* __restrict__ x, const uint32_t* __restrict__ qw,
                  const uint32_t* __restrict__ qz, const float* __restrict__ sc,
                  const float* __restrict__ bias, float* __restrict__ out)
{
    __shared__ _Float16 As[BM * LDA];   // A tile only; B never touches LDS

    const int tid  = threadIdx.x;
    // XCD-aware swizzle: same-XCD blocks get contiguous lids -> share m0 panel in L2
    const int lid  = (blockIdx.x & 7) * (NWG / 8) + (blockIdx.x >> 3);
    const int m0   = (lid / NXT) * BM;
    const int n0   = (lid % NXT) * BN;

    const int lane = tid & 63;
    const int wid  = tid >> 6;
    const int wr   = wid >> 1;        // 0..1
    const int wc   = wid & 1;         // 0..1
    const int lr   = lane & 15;
    const int lk   = lane >> 4;

    const int arow = tid >> 3;        // A staging row (0..31, +i*32)
    const int acp  = tid & 7;         // A staging col-octet

    f32x4 acc[4][4];
#pragma unroll
    for (int i = 0; i < 4; ++i)
#pragma unroll
        for (int j = 0; j < 4; ++j) {
            f32x4 z = {0.f, 0.f, 0.f, 0.f};
            acc[i][j] = z;
        }

    f32x4    areg[4][2];
    uint32_t breg[8], bregN[8];
    f16x2    ssv[4], zzv[4];
    float    s_nxt[4];
    uint32_t z_nxt[4];

    const int   ncb = n0 + wc * 64 + lr;      // this lane's base column
    const int   shz = 4 * (lr & 7);           // qzeros nibble shift (same for all j)
    const float* xbase = x + (size_t)(m0 + arow) * K_DIM + acp * 8;

    // ---------------- pre-loop prefetch (kt = 0) ----------------
#pragma unroll
    for (int i = 0; i < 4; ++i) {
        const float* src = xbase + (size_t)(i * 32) * K_DIM;
        areg[i][0] = *(const f32x4*)(src);
        areg[i][1] = *(const f32x4*)(src + 4);
    }
    {
        const uint32_t* pB = qw + (size_t)lk * N_DIM + ncb;
#pragma unroll
        for (int j = 0; j < 4; ++j) bregN[j]     = pB[j * 16];
#pragma unroll
        for (int j = 0; j < 4; ++j) bregN[4 + j] = pB[(size_t)4 * N_DIM + j * 16];
    }
#pragma unroll
    for (int j = 0; j < 4; ++j) {             // group 0 raw scale/zero
        s_nxt[j] = sc[ncb + j * 16];
        z_nxt[j] = qz[(ncb >> 3) + j * 2];
    }

    for (int kt = 0; kt < NT; ++kt) {
        if ((kt & 1) == 0) {                  // new group every 2 K-tiles (GROUP=128)
#pragma unroll
            for (int j = 0; j < 4; ++j) {
                uint32_t zn = (z_nxt[j] >> shz) & 15u;
                _Float16 zh = (_Float16)(float)(1024u + zn);
                _Float16 sh = (_Float16)s_nxt[j];
                f16x2 zp = {zh, zh}; zzv[j] = zp;
                f16x2 sp = {sh, sh}; ssv[j] = sp;
            }
        }

        __syncthreads();                      // all waves done reading prev A tile
        // stage A: fp32 -> f16 pairs (j, j+4) to match dq_word's k-permutation
#pragma unroll
        for (int i = 0; i < 4; ++i) {
            H8 v;
#pragma unroll
            for (int j = 0; j < 4; ++j)
                v.p[j] = __builtin_bit_cast(f16x2,
                           __builtin_amdgcn_cvt_pkrtz(areg[i][0][j], areg[i][1][j]));
            *(f16x8*)&As[(arow + i * 32) * LDA + acp * 8] = v.v;
        }
        __syncthreads();                      // A tile ready

#pragma unroll
        for (int q = 0; q < 8; ++q) breg[q] = bregN[q];

        if (kt + 1 < NT) {                    // prefetch next K-tile
            const float* ap = xbase + (kt + 1) * BK;
#pragma unroll
            for (int i = 0; i < 4; ++i) {
                const float* src = ap + (size_t)(i * 32) * K_DIM;
                areg[i][0] = *(const f32x4*)(src);
                areg[i][1] = *(const f32x4*)(src + 4);
            }
            const uint32_t* pBn = qw + (size_t)((kt + 1) * 8 + lk) * N_DIM + ncb;
#pragma unroll
            for (int j = 0; j < 4; ++j) bregN[j]     = pBn[j * 16];
#pragma unroll
            for (int j = 0; j < 4; ++j) bregN[4 + j] = pBn[(size_t)4 * N_DIM + j * 16];
            if (kt & 1) {                     // raw scale/zero for next group
                const int g = (kt + 1) >> 1;
#pragma unroll
                for (int j = 0; j < 4; ++j) {
                    s_nxt[j] = sc[(size_t)g * N_DIM + ncb + j * 16];
                    z_nxt[j] = qz[(size_t)g * NZW + (ncb >> 3) + j * 2];
                }
            }
        }

        // compute: A from LDS, B dequanted straight into fragment regs
#pragma unroll
        for (int ks = 0; ks < 2; ++ks) {
            f16x8 af[4], bf[4];
#pragma unroll
            for (int i = 0; i < 4; ++i)
                af[i] = *(const f16x8*)&As[(wr * 64 + i * 16 + lr) * LDA + ks * 32 + lk * 8];
#pragma unroll
            for (int j = 0; j < 4; ++j)
                bf[j] = dq_word(breg[ks * 4 + j], ssv[j], zzv[j]);
#pragma unroll
            for (int i = 0; i < 4; ++i)
#pragma unroll
                for (int j = 0; j < 4; ++j)
                    acc[i][j] = __builtin_amdgcn_mfma_f32_16x16x32_f16(af[i], bf[j], acc[i][j], 0, 0, 0);
        }
    }

    // epilogue: C/D layout col = lane&15, row = (lane>>4)*4 + reg
    const int ccol0 = n0 + wc * 64 + lr;
    float bj[4];
#pragma unroll
    for (int j = 0; j < 4; ++j) bj[j] = bias[ccol0 + j * 16];

#pragma unroll
    for (int i = 0; i < 4; ++i) {
        const int rbase = m0 + wr * 64 + i * 16 + lk * 4;
#pragma unroll
        for (int j = 0; j < 4; ++j) {
            const int col = ccol0 + j * 16;
#pragma unroll
            for (int r = 0; r < 4; ++r)
                out[(size_t)(rbase + r) * N_DIM + col] = acc[i][j][r] + bj[j];
        }
    }
}

extern "C" void kernel_launch(void* const* d_in, const int* in_sizes, int n_in,
                              void* d_out, int out_size, void* d_ws, size_t ws_size,
                              hipStream_t stream) {
    const float*    xp = (const float*)d_in[0];
    const uint32_t* qw = (const uint32_t*)d_in[1];
    const uint32_t* qz = (const uint32_t*)d_in[2];
    const float*    sc = (const float*)d_in[3];
    const float*    bi = (const float*)d_in[4];
    float*          op = (float*)d_out;
    (void)in_sizes; (void)n_in; (void)d_ws; (void)ws_size; (void)out_size;

    qgemm_kernel<<<dim3(NWG), dim3(256), 0, stream>>>(xp, qw, qz, sc, bi, op);
}